// Round 1
// baseline (20710.002 us; speedup 1.0000x reference)
//
#include <hip/hip_runtime.h>
#include <math.h>

#define TT 512
#define BB 256
#define EE 300
#define KK 9
#define HH 256
#define GG 1024   // 4*H
#define TCH 64    // time chunk for xg staging

// ---------------- xg = gather(emb) @ W_ih^T + bias  (one TCH chunk) ----------------
// grid: (TCH*BB/64, GG/64), block 256. Tile 64x64, BK=60 (5 chunks of K=300).
__global__ __launch_bounds__(256) void gemm_xg_kernel(
    const int* __restrict__ ids, const float* __restrict__ emb,
    const float* __restrict__ W_ih, const float* __restrict__ bias,
    float* __restrict__ xg, int t0)
{
  __shared__ float As[64][61];
  __shared__ float Bs[64][61];
  __shared__ int tokid[64];
  const int tid = threadIdx.x;
  const int ty = tid >> 4, tx = tid & 15;
  const int m0 = blockIdx.x * 64;          // chunk-local token row base
  const int n0 = blockIdx.y * 64;          // gate-col base
  const int tokBase = t0 * BB + m0;        // global token index base
  if (tid < 64) tokid[tid] = ids[tokBase + tid];
  __syncthreads();
  float acc[4][4] = {};
  for (int k0 = 0; k0 < EE; k0 += 60) {
    for (int idx = tid; idx < 64 * 60; idx += 256) {
      int r = idx / 60, kk = idx - r * 60;
      As[r][kk] = emb[(size_t)tokid[r] * EE + k0 + kk];
    }
    for (int idx = tid; idx < 64 * 60; idx += 256) {
      int r = idx / 60, kk = idx - r * 60;
      Bs[r][kk] = W_ih[(size_t)(n0 + r) * EE + k0 + kk];
    }
    __syncthreads();
    #pragma unroll 4
    for (int kk = 0; kk < 60; ++kk) {
      float a0 = As[ty*4+0][kk], a1 = As[ty*4+1][kk];
      float a2 = As[ty*4+2][kk], a3 = As[ty*4+3][kk];
      float w0 = Bs[tx*4+0][kk], w1 = Bs[tx*4+1][kk];
      float w2 = Bs[tx*4+2][kk], w3 = Bs[tx*4+3][kk];
      acc[0][0] += a0*w0; acc[0][1] += a0*w1; acc[0][2] += a0*w2; acc[0][3] += a0*w3;
      acc[1][0] += a1*w0; acc[1][1] += a1*w1; acc[1][2] += a1*w2; acc[1][3] += a1*w3;
      acc[2][0] += a2*w0; acc[2][1] += a2*w1; acc[2][2] += a2*w2; acc[2][3] += a2*w3;
      acc[3][0] += a3*w0; acc[3][1] += a3*w1; acc[3][2] += a3*w2; acc[3][3] += a3*w3;
    }
    __syncthreads();
  }
  const int n = n0 + tx*4;
  #pragma unroll
  for (int i = 0; i < 4; ++i) {
    int r = m0 + ty*4 + i;
    float4 o;
    o.x = acc[i][0] + bias[n+0];
    o.y = acc[i][1] + bias[n+1];
    o.z = acc[i][2] + bias[n+2];
    o.w = acc[i][3] + bias[n+3];
    *(float4*)&xg[(size_t)r * GG + n] = o;
  }
}

// ---------------- one LSTM time step (one direction) ----------------
// grid: (16 j-tiles, 8 b-tiles), block 256 = 16 tr x 16 tb.
// Block computes gates for 32 batches x (4 gates x 16 j). Thread: 2 batches x (i,f,g,o of one j).
__global__ __launch_bounds__(256) void lstm_step_kernel(
    const float* __restrict__ xgc,    // chunk base [(tl*B + b)*G + g]
    const float* __restrict__ W_hh,   // (1024, 256)
    const int* __restrict__ lens,
    float* __restrict__ hs,           // (T, B, H)
    float* __restrict__ cbuf,         // (B, H)
    int t, int tl, int first, int hprev_t)
{
  __shared__ float AL[32][132];   // h_prev tile: 32 batches x 128 k (half), pad 4
  __shared__ float WL[64][132];   // W rows: (q*16+jj) x 128 k (half), pad 4
  const int tid = threadIdx.x;
  const int tr = tid >> 4;        // 0..15 -> j within tile
  const int tb = tid & 15;        // 0..15 -> batch lane
  const int jt = blockIdx.x;      // 0..15
  const int bt = blockIdx.y;      // 0..7
  const int bbase = bt * 32;
  const int j = jt * 16 + tr;     // 0..255
  float acc0[4] = {0.f,0.f,0.f,0.f};
  float acc1[4] = {0.f,0.f,0.f,0.f};

  for (int kh = 0; kh < 2; ++kh) {
    for (int idx = tid; idx < 32 * 32; idx += 256) {       // h_prev: 32 b x 32 float4
      int bl = idx >> 5, k4 = idx & 31;
      float4 v;
      if (first) { v.x=0.f; v.y=0.f; v.z=0.f; v.w=0.f; }
      else v = *(const float4*)&hs[((size_t)hprev_t * BB + bbase + bl) * HH + kh*128 + k4*4];
      *(float4*)&AL[bl][k4*4] = v;
    }
    for (int idx = tid; idx < 64 * 32; idx += 256) {       // W: 64 rows x 32 float4
      int row = idx >> 5, k4 = idx & 31;
      int q = row >> 4, jj = row & 15;
      int grow = q * 256 + jt * 16 + jj;
      float4 w = *(const float4*)&W_hh[(size_t)grow * HH + kh*128 + k4*4];
      *(float4*)&WL[row][k4*4] = w;
    }
    __syncthreads();
    #pragma unroll 8
    for (int k4 = 0; k4 < 32; ++k4) {
      float4 a0 = *(const float4*)&AL[tb][k4*4];
      float4 a1 = *(const float4*)&AL[tb+16][k4*4];
      #pragma unroll
      for (int q = 0; q < 4; ++q) {
        float4 w = *(const float4*)&WL[q*16 + tr][k4*4];
        acc0[q] += a0.x*w.x; acc0[q] += a0.y*w.y; acc0[q] += a0.z*w.z; acc0[q] += a0.w*w.w;
        acc1[q] += a1.x*w.x; acc1[q] += a1.y*w.y; acc1[q] += a1.z*w.z; acc1[q] += a1.w*w.w;
      }
    }
    __syncthreads();
  }

  #pragma unroll
  for (int half = 0; half < 2; ++half) {
    const int bg = bbase + tb + half*16;
    const float* acc = half ? acc1 : acc0;
    const float* xrow = &xgc[((size_t)tl * BB + bg) * GG];
    float gi = acc[0] + xrow[j];
    float gf = acc[1] + xrow[256 + j];
    float gg = acc[2] + xrow[512 + j];
    float go = acc[3] + xrow[768 + j];
    float c_old = first ? 0.f : cbuf[(size_t)bg * HH + j];
    float h_old = first ? 0.f : hs[((size_t)hprev_t * BB + bg) * HH + j];
    float si = 1.f / (1.f + expf(-gi));
    float sf = 1.f / (1.f + expf(-gf));
    float so = 1.f / (1.f + expf(-go));
    float cn = sf * c_old + si * tanhf(gg);
    float hn = so * tanhf(cn);
    bool m = t < lens[bg];
    float ho = m ? hn : h_old;
    float co = m ? cn : c_old;
    hs[((size_t)t * BB + bg) * HH + j] = ho;
    cbuf[(size_t)bg * HH + j] = co;
  }
}

// ---------------- emissions (one half of HID): emis[b][t][k] (+)= W_out[:,half]·hs ----------------
// grid: T*B/4 blocks, 256 thr (4 waves, one token each)
__global__ __launch_bounds__(256) void emis_half_kernel(
    const float* __restrict__ hs, const float* __restrict__ W_out,
    const float* __restrict__ b_out, float* __restrict__ emis, int half)
{
  const int lane = threadIdx.x & 63;
  const int wid  = threadIdx.x >> 6;
  const int token = blockIdx.x * 4 + wid;
  const int t = token >> 8, b = token & 255;
  float4 h4 = *(const float4*)&hs[(size_t)token * HH + lane*4];
  float r[KK];
  #pragma unroll
  for (int k = 0; k < KK; ++k) {
    float4 w4 = *(const float4*)&W_out[(size_t)k * 512 + half*256 + lane*4];
    r[k] = h4.x*w4.x + h4.y*w4.y + h4.z*w4.z + h4.w*w4.w;
  }
  #pragma unroll
  for (int k = 0; k < KK; ++k)
    #pragma unroll
    for (int off = 32; off; off >>= 1) r[k] += __shfl_down(r[k], off);
  if (lane == 0) {
    float* e = &emis[((size_t)b * TT + t) * KK];
    if (half == 0) {
      #pragma unroll
      for (int k = 0; k < KK; ++k) e[k] = b_out[k] + r[k];
    } else {
      #pragma unroll
      for (int k = 0; k < KK; ++k) e[k] += r[k];
    }
  }
}

// ---------------- CRF: num, alpha scan, viterbi + backtrace. 1 block (64 thr) per batch ----------------
__global__ __launch_bounds__(64) void crf_kernel(
    const float* __restrict__ emis,    // [b][t][k]
    const int* __restrict__ labels,    // (T, B)
    const int* __restrict__ lens,
    const float* __restrict__ start_trans,
    const float* __restrict__ end_trans,
    const float* __restrict__ trans,   // (K, K)
    float* __restrict__ numden,
    float* __restrict__ outp)          // d_out: [0]=loss, [1..]=preds
{
  const int b = blockIdx.x;
  const int lane = threadIdx.x;
  __shared__ __align__(16) float em[TT * KK];
  __shared__ unsigned char hist[TT * KK];   // (T-1)*9 used
  const float* eb = &emis[(size_t)b * TT * KK];
  for (int i = lane; i < TT*KK/4; i += 64)
    ((float4*)em)[i] = ((const float4*)eb)[i];
  const int len = lens[b];
  const int k = lane < KK ? lane : KK-1;
  float tc[KK];
  #pragma unroll
  for (int jj = 0; jj < KK; ++jj) tc[jj] = trans[jj*KK + k];
  __syncthreads();

  // ---- numerator (lane-strided over t, fixed-order reduce) ----
  float nacc = 0.f;
  for (int t = lane; t < TT; t += 64) {
    int lt = labels[t*BB + b];
    if (t == 0) nacc += start_trans[lt] + em[lt];
    else if (t < len) nacc += trans[labels[(t-1)*BB + b]*KK + lt] + em[t*KK + lt];
  }
  if (lane == 0) nacc += end_trans[labels[(size_t)(len-1)*BB + b]];
  #pragma unroll
  for (int off = 32; off; off >>= 1) nacc += __shfl_down(nacc, off);

  // ---- alpha (logsumexp) + viterbi (max/argmax) scans, state k per lane, replicated vectors ----
  float alpha[KK], score[KK];
  #pragma unroll
  for (int jj = 0; jj < KK; ++jj) {
    float v = start_trans[jj] + em[jj];
    alpha[jj] = v; score[jj] = v;
  }
  for (int t = 1; t < TT; ++t) {
    float av[KK]; float mx = -1e30f;
    #pragma unroll
    for (int jj = 0; jj < KK; ++jj) { av[jj] = alpha[jj] + tc[jj]; mx = fmaxf(mx, av[jj]); }
    float s = 0.f;
    #pragma unroll
    for (int jj = 0; jj < KK; ++jj) s += expf(av[jj] - mx);
    float e_tk = em[t*KK + k];
    float na = mx + logf(s) + e_tk;
    float best = -1e30f; int bj = 0;
    #pragma unroll
    for (int jj = 0; jj < KK; ++jj) {
      float sv = score[jj] + tc[jj];
      if (sv > best) { best = sv; bj = jj; }   // strict > = first-max (jnp.argmax)
    }
    float ns = best + e_tk;
    bool msk = t < len;
    na = msk ? na : alpha[k];
    ns = msk ? ns : score[k];
    if (lane < KK) hist[(t-1)*KK + lane] = (unsigned char)bj;
    #pragma unroll
    for (int jj = 0; jj < KK; ++jj) { alpha[jj] = __shfl(na, jj); score[jj] = __shfl(ns, jj); }
  }
  float dm = -1e30f;
  #pragma unroll
  for (int jj = 0; jj < KK; ++jj) dm = fmaxf(dm, alpha[jj] + end_trans[jj]);
  float dsum = 0.f;
  #pragma unroll
  for (int jj = 0; jj < KK; ++jj) dsum += expf(alpha[jj] + end_trans[jj] - dm);
  float denom = dm + logf(dsum);
  int bl_ = 0; float bs = -1e30f;
  #pragma unroll
  for (int jj = 0; jj < KK; ++jj) {
    float v = score[jj] + end_trans[jj];
    if (v > bs) { bs = v; bl_ = jj; }
  }
  if (lane == 0) numden[b] = nacc - denom;
  __syncthreads();
  if (lane == 0) {
    int tag = bl_;
    outp[1 + (size_t)(TT-1)*BB + b] = ((TT-1) < len) ? (float)bl_ : 0.f;
    for (int s = TT-2; s >= 0; --s) {
      tag = ((s+1) < len) ? (int)hist[s*KK + tag] : bl_;
      outp[1 + (size_t)s*BB + b] = (s < len) ? (float)tag : 0.f;
    }
  }
}

__global__ __launch_bounds__(256) void loss_reduce_kernel(
    const float* __restrict__ numden, float* __restrict__ out)
{
  __shared__ float sh[256];
  int tid = threadIdx.x;
  sh[tid] = numden[tid];
  __syncthreads();
  for (int s = 128; s > 0; s >>= 1) {
    if (tid < s) sh[tid] += sh[tid + s];
    __syncthreads();
  }
  if (tid == 0) out[0] = -sh[0];
}

extern "C" void kernel_launch(void* const* d_in, const int* in_sizes, int n_in,
                              void* d_out, int out_size, void* d_ws, size_t ws_size,
                              hipStream_t stream)
{
  const int*   ids    = (const int*)d_in[0];
  const int*   lens   = (const int*)d_in[1];
  const int*   labels = (const int*)d_in[2];
  const float* emb    = (const float*)d_in[3];
  const float* W_ih_f = (const float*)d_in[4];
  const float* W_hh_f = (const float*)d_in[5];
  const float* b_f    = (const float*)d_in[6];
  const float* W_ih_b = (const float*)d_in[7];
  const float* W_hh_b = (const float*)d_in[8];
  const float* b_b    = (const float*)d_in[9];
  const float* W_out  = (const float*)d_in[10];
  const float* b_out  = (const float*)d_in[11];
  const float* s_tr   = (const float*)d_in[12];
  const float* e_tr   = (const float*)d_in[13];
  const float* trans  = (const float*)d_in[14];
  float* out = (float*)d_out;

  // workspace layout (floats): xg chunk | hs | c | emis | numden  (~197 MiB total)
  float* ws     = (float*)d_ws;
  float* xgc    = ws;
  float* hs     = xgc  + (size_t)TCH * BB * GG;   // 16,777,216
  float* cbuf   = hs   + (size_t)TT  * BB * HH;   // +33,554,432
  float* emis   = cbuf + (size_t)BB  * HH;        // +65,536
  float* numden = emis + (size_t)BB  * TT * KK;   // +1,179,648

  dim3 gemmGrid(TCH*BB/64, GG/64);
  dim3 stepGrid(16, 8);

  // forward direction
  for (int ch = 0; ch < TT/TCH; ++ch) {
    gemm_xg_kernel<<<gemmGrid, 256, 0, stream>>>(ids, emb, W_ih_f, b_f, xgc, ch*TCH);
    for (int t = ch*TCH; t < ch*TCH + TCH; ++t)
      lstm_step_kernel<<<stepGrid, 256, 0, stream>>>(xgc, W_hh_f, lens, hs, cbuf,
                                                     t, t - ch*TCH, t == 0 ? 1 : 0, t - 1);
  }
  emis_half_kernel<<<TT*BB/4, 256, 0, stream>>>(hs, W_out, b_out, emis, 0);

  // backward direction (reuses xgc/hs/cbuf)
  for (int ch = TT/TCH - 1; ch >= 0; --ch) {
    gemm_xg_kernel<<<gemmGrid, 256, 0, stream>>>(ids, emb, W_ih_b, b_b, xgc, ch*TCH);
    for (int t = ch*TCH + TCH - 1; t >= ch*TCH; --t)
      lstm_step_kernel<<<stepGrid, 256, 0, stream>>>(xgc, W_hh_b, lens, hs, cbuf,
                                                     t, t - ch*TCH, t == TT-1 ? 1 : 0, t + 1);
  }
  emis_half_kernel<<<TT*BB/4, 256, 0, stream>>>(hs, W_out, b_out, emis, 1);

  crf_kernel<<<BB, 64, 0, stream>>>(emis, labels, lens, s_tr, e_tr, trans, numden, out);
  loss_reduce_kernel<<<1, 256, 0, stream>>>(numden, out);
}